// Round 14
// baseline (1535.107 us; speedup 1.0000x reference)
//
#include <hip/hip_runtime.h>
#include <stdint.h>

#define M_DIM 8192
#define N_DIM 4096
#define K_DIM 4096
#define CBN   (K_DIM/8)   // 512 column groups per row

typedef __attribute__((ext_vector_type(4)))  int   i32x4;
typedef __attribute__((ext_vector_type(16))) char  i8x16;

#define AS_GLOBAL(p) (const __attribute__((address_space(1))) void*)(p)
#define AS_LDS(p)    (__attribute__((address_space(3))) void*)(p)

// ---------------------------------------------------------------------------
// Kernel 1: per (ob, cb) pick top-4 columns (of 8) by L1 mass over 64 rows.
// (unchanged — mask decided on exact f32 weights)
// ---------------------------------------------------------------------------
__global__ __launch_bounds__(256) void venom_sel(const float* __restrict__ W,
                                                 uint16_t* __restrict__ sel) {
    int t   = threadIdx.x;
    int ob  = blockIdx.x;
    int col = blockIdx.y * 256 + t;
    const float* p = W + (size_t)(ob * 64) * K_DIM + col;
    double s = 0.0;
    #pragma unroll 16
    for (int r = 0; r < 64; ++r) s += fabsf(p[(size_t)r * K_DIM]);

    int lane = t & 63;
    int base = lane & ~7;
    double sc[8];
    #pragma unroll
    for (int j = 0; j < 8; ++j) sc[j] = __shfl(s, base + j, 64);

    uint32_t packed = 0;
    #pragma unroll
    for (int c = 0; c < 8; ++c) {
        int rank = 0;
        #pragma unroll
        for (int j = 0; j < 8; ++j)
            rank += (sc[j] > sc[c]) || (sc[j] == sc[c] && j < c);
        if (rank < 4) packed |= (uint32_t)c << (4 * rank);
    }
    if ((lane & 7) == 0) {
        int cb = col >> 3;
        sel[ob * CBN + cb] = (uint16_t)packed;
    }
}

// ---------------------------------------------------------------------------
// Kernel 2: masked weight -> int8 with per-output-row symmetric scale.
// ---------------------------------------------------------------------------
__global__ __launch_bounds__(256) void venom_packq(const float* __restrict__ W,
                                                   const uint16_t* __restrict__ sel,
                                                   int8_t* __restrict__ Wq,
                                                   float* __restrict__ sw) {
    __shared__ float red[4];
    int o = blockIdx.x;
    const float* rowp = W + (size_t)o * K_DIM;
    float mv[16];
    float m = 0.0f;
    #pragma unroll
    for (int h = 0; h < 2; ++h) {
        int cb = threadIdx.x * 2 + h;
        uint32_t pk = sel[(o >> 6) * CBN + cb];
        const float* p = rowp + cb * 8;
        float4 a = *(const float4*)p;
        float4 b = *(const float4*)(p + 4);
        float w[8] = {a.x, a.y, a.z, a.w, b.x, b.y, b.z, b.w};
        int   c[4]; float v[4];
        #pragma unroll
        for (int pz = 0; pz < 4; ++pz) {
            c[pz] = (pk >> (4 * pz)) & 7;
            v[pz] = fabsf(w[c[pz]]);
        }
        uint32_t keep = 0;
        #pragma unroll
        for (int pz = 0; pz < 4; ++pz) {
            int cnt = 0;
            #pragma unroll
            for (int q = 0; q < 4; ++q)
                cnt += (v[q] > v[pz]) || (v[q] == v[pz] && q < pz);
            if (cnt < 2) keep |= 1u << c[pz];
        }
        #pragma unroll
        for (int j = 0; j < 8; ++j) {
            float x = ((keep >> j) & 1) ? w[j] : 0.0f;
            mv[h * 8 + j] = x;
            m = fmaxf(m, fabsf(x));
        }
    }
    #pragma unroll
    for (int off = 32; off >= 1; off >>= 1) m = fmaxf(m, __shfl_xor(m, off, 64));
    int lane = threadIdx.x & 63, wid = threadIdx.x >> 6;
    if (lane == 0) red[wid] = m;
    __syncthreads();
    m = fmaxf(fmaxf(red[0], red[1]), fmaxf(red[2], red[3]));
    float inv = m > 0.0f ? 127.0f / m : 0.0f;

    i8x16 q;
    #pragma unroll
    for (int j = 0; j < 16; ++j) {
        float qq = rintf(mv[j] * inv);
        qq = fminf(127.0f, fmaxf(-127.0f, qq));
        q[j] = (char)(int)qq;
    }
    *(i8x16*)(Wq + (size_t)o * K_DIM + threadIdx.x * 16) = q;
    if (threadIdx.x == 0) sw[o] = m > 0.0f ? m / 127.0f : 1.0f;
}

// ---------------------------------------------------------------------------
// Kernel 3: x f32 -> int8 with per-row symmetric scale. One block per row.
// ---------------------------------------------------------------------------
__global__ __launch_bounds__(256) void xq_kernel(const float* __restrict__ X,
                                                 int8_t* __restrict__ Xq,
                                                 float* __restrict__ sx) {
    __shared__ float red[4];
    int row = blockIdx.x;
    const float4* p = (const float4*)(X + (size_t)row * K_DIM) + threadIdx.x * 4;
    float4 v0 = p[0], v1 = p[1], v2 = p[2], v3 = p[3];
    float vv[16] = {v0.x, v0.y, v0.z, v0.w, v1.x, v1.y, v1.z, v1.w,
                    v2.x, v2.y, v2.z, v2.w, v3.x, v3.y, v3.z, v3.w};
    float m = 0.0f;
    #pragma unroll
    for (int j = 0; j < 16; ++j) m = fmaxf(m, fabsf(vv[j]));
    #pragma unroll
    for (int off = 32; off >= 1; off >>= 1) m = fmaxf(m, __shfl_xor(m, off, 64));
    int lane = threadIdx.x & 63, wid = threadIdx.x >> 6;
    if (lane == 0) red[wid] = m;
    __syncthreads();
    m = fmaxf(fmaxf(red[0], red[1]), fmaxf(red[2], red[3]));
    float inv = m > 0.0f ? 127.0f / m : 0.0f;

    i8x16 q;
    #pragma unroll
    for (int j = 0; j < 16; ++j) {
        float qq = rintf(vv[j] * inv);
        qq = fminf(127.0f, fmaxf(-127.0f, qq));
        q[j] = (char)(int)qq;
    }
    *(i8x16*)(Xq + (size_t)row * K_DIM + threadIdx.x * 16) = q;
    if (threadIdx.x == 0) sx[row] = m > 0.0f ? m / 127.0f : 1.0f;
}

// ---------------------------------------------------------------------------
// Kernel 4: 256x256 int8 GEMM, 2-BLOCKS-PER-CU variant. LDS cut 128->64 KB
// (plain double-buffer, 2 regions, stage-lead 1, CKPT0 per slice) +
// __launch_bounds__(512, 4): 4 waves/EU -> 2 co-resident blocks per CU
// (LDS 2x64=128<=160 KB, VGPR <=128, 16 waves <=32). Rationale: 7 intra-block
// schedules all hit the serial wall (MFMA 1306cy + LDS 1152cy per slice,
// barrier-locked). Independent blocks share no barriers -> block A's MFMA
// overlaps block B's LDS/drain window (m97's multi-block implicit overlap).
// The per-slice full drain (CKPT0) is covered by the other block's compute.
// SP s: { 12 ds_read (region s&1) | stageA(s+1 -> region (s+1)&1) | lgkm(4) |
//         16 MFMA Mh0 | stageB(s+1) | lgkm(0) | 16 MFMA Mh1 | CKPT0 | BAR }
// Ledger (round-2-proven dbuf): R@s: staged @s-1, drained CKPT0@s-1 + BAR.
//   W-after-R: stage s+1 overwrites region of s-1, whose reads drained at
//   lgkm(0) @SP s-1 before BAR@s-1. Tail: SP63 no stage, no CKPT.
// Frags 16x16x64 i8; XOR 16B-chunk swizzle (0 conflicts); XCD block swizzle.
// ---------------------------------------------------------------------------
__global__ __launch_bounds__(512, 4) void gemm256_i8(const int8_t* __restrict__ A,
                                                     const int8_t* __restrict__ B,
                                                     const float* __restrict__ sx,
                                                     const float* __restrict__ sw,
                                                     const float* __restrict__ bias,
                                                     float* __restrict__ C) {
    __shared__ __align__(16) unsigned char smem[65536]; // A:[0,32K) B:[32K,64K)

    int t    = threadIdx.x;
    int wid  = t >> 6;
    int lane = t & 63;
    int l16  = lane & 15;
    int lk   = lane >> 4;
    int wm   = wid >> 2;     // wave row-half (128 rows)
    int wn   = wid & 3;      // wave col-quarter (64 cols)

    // XCD-aware bijective swizzle (512 blocks % 8 == 0)
    int bid = blockIdx.x;
    int swz = (bid & 7) * ((int)gridDim.x >> 3) + (bid >> 3);
    int bm  = swz >> 4;
    int bn  = swz & 15;

    // staging: thread t covers row r=t>>2 (and r+128); stored 16B chunk t&3
    // holds logical chunk (t&3)^((r>>1)&3) = (t&3)^((t>>3)&3)
    int gch = ((t & 3) ^ ((t >> 3) & 3)) * 16;
    const int8_t* agbase = A + (size_t)(bm * 256 + (t >> 2)) * K_DIM + gch;
    const int8_t* bgbase = B + (size_t)(bn * 256 + (t >> 2)) * K_DIM + gch;

    auto stageA2 = [&](int slice) {
        const int8_t* ga = agbase + slice * 64;
        char* la = (char*)smem + (slice & 1) * 16384 + wid * 1024;
        __builtin_amdgcn_global_load_lds(AS_GLOBAL(ga), AS_LDS(la), 16, 0, 0);
        __builtin_amdgcn_global_load_lds(AS_GLOBAL(ga + (size_t)128 * K_DIM), AS_LDS(la + 8192), 16, 0, 0);
    };
    auto stageB2 = [&](int slice) {
        const int8_t* gb = bgbase + slice * 64;
        char* lb = (char*)smem + 32768 + (slice & 1) * 16384 + wid * 1024;
        __builtin_amdgcn_global_load_lds(AS_GLOBAL(gb), AS_LDS(lb), 16, 0, 0);
        __builtin_amdgcn_global_load_lds(AS_GLOBAL(gb + (size_t)128 * K_DIM), AS_LDS(lb + 8192), 16, 0, 0);
    };

    // read-side: row R = base+l16, 16B chunk lk -> phys chunk lk^((l16>>1)&3)
    int koff = ((lk ^ ((l16 >> 1) & 3)) << 4);
    const char* ardb = (const char*)smem + (wm * 128 + l16) * 64 + koff;
    const char* brdb = (const char*)smem + 32768 + (wn * 64 + l16) * 64 + koff;

    i32x4 acc[8][4] = {};
    i32x4 af0[4], af1[4], bfr[4];

#define LGKM(N) { asm volatile("s_waitcnt lgkmcnt(" #N ")" ::: "memory");            \
                  __builtin_amdgcn_sched_barrier(0); }
#define CKPT0() { asm volatile("s_waitcnt vmcnt(0)" ::: "memory");                   \
                  __builtin_amdgcn_sched_barrier(0); }
#define BAR()   { __builtin_amdgcn_s_barrier(); __builtin_amdgcn_sched_barrier(0); }

    // SP body. RN: region (s&1). SS: slice staged (s+1). DOSTAGE. CK: 1/0.
#define SP(RN, SS, DOSTAGE, CK)                                                      \
    {                                                                                \
        const char* abase = ardb + (RN) * 16384;                                     \
        const char* bbase = brdb + (RN) * 16384;                                     \
        _Pragma("unroll")                                                            \
        for (int g = 0; g < 4; ++g) bfr[g] = *(const i32x4*)(bbase + g * 1024);      \
        _Pragma("unroll")                                                            \
        for (int i = 0; i < 4; ++i) af0[i] = *(const i32x4*)(abase + i * 1024);      \
        _Pragma("unroll")                                                            \
        for (int i = 0; i < 4; ++i) af1[i] = *(const i32x4*)(abase + 4096 + i * 1024); \
        if (DOSTAGE) stageA2(SS);                                                    \
        LGKM(4)                                                                      \
        __builtin_amdgcn_s_setprio(1);                                               \
        _Pragma("unroll")                                                            \
        for (int i = 0; i < 4; ++i)                                                  \
            _Pragma("unroll")                                                        \
            for (int g = 0; g < 4; ++g)                                              \
                acc[i][g] = __builtin_amdgcn_mfma_i32_16x16x64_i8(af0[i], bfr[g], acc[i][g], 0, 0, 0); \
        __builtin_amdgcn_s_setprio(0);                                               \
        __builtin_amdgcn_sched_barrier(0);                                           \
        if (DOSTAGE) stageB2(SS);                                                    \
        LGKM(0)                                                                      \
        __builtin_amdgcn_s_setprio(1);                                               \
        _Pragma("unroll")                                                            \
        for (int i = 0; i < 4; ++i)                                                  \
            _Pragma("unroll")                                                        \
            for (int g = 0; g < 4; ++g)                                              \
                acc[4+i][g] = __builtin_amdgcn_mfma_i32_16x16x64_i8(af1[i], bfr[g], acc[4+i][g], 0, 0, 0); \
        __builtin_amdgcn_s_setprio(0);                                               \
        __builtin_amdgcn_sched_barrier(0);                                           \
        if (CK) { CKPT0() }                                                          \
        BAR()                                                                        \
    }

    // prologue: slice 0 -> region 0; drain; sync
    stageA2(0); stageB2(0);
    CKPT0()
    BAR()

    // 64 slices of 64 K-bytes; stage s+1 at SP s for s <= 62
    for (int s2 = 0; s2 < 31; ++s2) {
        int s = s2 * 2;
        SP(0, s + 1, 1, 1)
        SP(1, s + 2, 1, 1)
    }
    SP(0, 63, 1, 1)   // s=62: stage 63
    SP(1, 0,  0, 0)   // s=63: no stage, nothing outstanding

    // epilogue: C/D layout col = lane&15, row = (lane>>4)*4 + reg.
    // out = sx[row]*sw[col]*acc + bias.
    int    colb = bn * 256 + wn * 64;
    size_t rowb = (size_t)bm * 256 + wm * 128 + (lk << 2);
    float sxv[8][4];
    #pragma unroll
    for (int f = 0; f < 8; ++f)
        #pragma unroll
        for (int rg = 0; rg < 4; ++rg)
            sxv[f][rg] = sx[rowb + f * 16 + rg];
    #pragma unroll
    for (int g = 0; g < 4; ++g) {
        int col = colb + g * 16 + l16;
        float scw = sw[col];
        float bv  = bias[col];
        #pragma unroll
        for (int f = 0; f < 8; ++f) {
            size_t r0 = rowb + f * 16;
            #pragma unroll
            for (int rg = 0; rg < 4; ++rg)
                C[(r0 + rg) * N_DIM + col] = (float)acc[f][g][rg] * (sxv[f][rg] * scw) + bv;
        }
    }
}

extern "C" void kernel_launch(void* const* d_in, const int* in_sizes, int n_in,
                              void* d_out, int out_size, void* d_ws, size_t ws_size,
                              hipStream_t stream) {
    const float* x    = (const float*)d_in[0];
    const float* W    = (const float*)d_in[1];
    const float* bias = (const float*)d_in[2];
    float* out = (float*)d_out;

    char* ws = (char*)d_ws;
    int8_t*   xq  = (int8_t*)ws;                                             // 32 MB
    int8_t*   wq  = (int8_t*)(ws + (size_t)M_DIM * K_DIM);                   // 16 MB
    uint16_t* sel = (uint16_t*)(ws + (size_t)M_DIM * K_DIM
                                   + (size_t)N_DIM * K_DIM);                 // 64 KB
    float*    sx  = (float*)((char*)sel + (size_t)(M_DIM / 64) * CBN * 2);   // 32 KB
    float*    sw  = (float*)((char*)sx + (size_t)M_DIM * 4);                 // 16 KB

    venom_sel  <<<dim3(64, 16), 256, 0, stream>>>(W, sel);
    venom_packq<<<dim3(N_DIM), 256, 0, stream>>>(W, sel, wq, sw);
    xq_kernel  <<<dim3(M_DIM), 256, 0, stream>>>(x, xq, sx);
    gemm256_i8 <<<dim3((M_DIM / 256) * (N_DIM / 256)), 512, 0, stream>>>(xq, wq, sx, sw, bias, out);
}

// Round 15
// 211.211 us; speedup vs baseline: 7.2681x; 7.2681x over previous
//
#include <hip/hip_runtime.h>
#include <stdint.h>

#define M_DIM 8192
#define N_DIM 4096
#define K_DIM 4096
#define CBN   (K_DIM/8)   // 512 column groups per row

typedef __attribute__((ext_vector_type(4)))  int   i32x4;
typedef __attribute__((ext_vector_type(16))) char  i8x16;

#define AS_GLOBAL(p) (const __attribute__((address_space(1))) void*)(p)
#define AS_LDS(p)    (__attribute__((address_space(3))) void*)(p)

// ---------------------------------------------------------------------------
// Kernel 1: per (ob, cb) pick top-4 columns (of 8) by L1 mass over 64 rows.
// ---------------------------------------------------------------------------
__global__ __launch_bounds__(256) void venom_sel(const float* __restrict__ W,
                                                 uint16_t* __restrict__ sel) {
    int t   = threadIdx.x;
    int ob  = blockIdx.x;
    int col = blockIdx.y * 256 + t;
    const float* p = W + (size_t)(ob * 64) * K_DIM + col;
    double s = 0.0;
    #pragma unroll 16
    for (int r = 0; r < 64; ++r) s += fabsf(p[(size_t)r * K_DIM]);

    int lane = t & 63;
    int base = lane & ~7;
    double sc[8];
    #pragma unroll
    for (int j = 0; j < 8; ++j) sc[j] = __shfl(s, base + j, 64);

    uint32_t packed = 0;
    #pragma unroll
    for (int c = 0; c < 8; ++c) {
        int rank = 0;
        #pragma unroll
        for (int j = 0; j < 8; ++j)
            rank += (sc[j] > sc[c]) || (sc[j] == sc[c] && j < c);
        if (rank < 4) packed |= (uint32_t)c << (4 * rank);
    }
    if ((lane & 7) == 0) {
        int cb = col >> 3;
        sel[ob * CBN + cb] = (uint16_t)packed;
    }
}

// ---------------------------------------------------------------------------
// Kernel 2: masked weight -> int8 with per-output-row symmetric scale.
// ---------------------------------------------------------------------------
__global__ __launch_bounds__(256) void venom_packq(const float* __restrict__ W,
                                                   const uint16_t* __restrict__ sel,
                                                   int8_t* __restrict__ Wq,
                                                   float* __restrict__ sw) {
    __shared__ float red[4];
    int o = blockIdx.x;
    const float* rowp = W + (size_t)o * K_DIM;
    float mv[16];
    float m = 0.0f;
    #pragma unroll
    for (int h = 0; h < 2; ++h) {
        int cb = threadIdx.x * 2 + h;
        uint32_t pk = sel[(o >> 6) * CBN + cb];
        const float* p = rowp + cb * 8;
        float4 a = *(const float4*)p;
        float4 b = *(const float4*)(p + 4);
        float w[8] = {a.x, a.y, a.z, a.w, b.x, b.y, b.z, b.w};
        int   c[4]; float v[4];
        #pragma unroll
        for (int pz = 0; pz < 4; ++pz) {
            c[pz] = (pk >> (4 * pz)) & 7;
            v[pz] = fabsf(w[c[pz]]);
        }
        uint32_t keep = 0;
        #pragma unroll
        for (int pz = 0; pz < 4; ++pz) {
            int cnt = 0;
            #pragma unroll
            for (int q = 0; q < 4; ++q)
                cnt += (v[q] > v[pz]) || (v[q] == v[pz] && q < pz);
            if (cnt < 2) keep |= 1u << c[pz];
        }
        #pragma unroll
        for (int j = 0; j < 8; ++j) {
            float x = ((keep >> j) & 1) ? w[j] : 0.0f;
            mv[h * 8 + j] = x;
            m = fmaxf(m, fabsf(x));
        }
    }
    #pragma unroll
    for (int off = 32; off >= 1; off >>= 1) m = fmaxf(m, __shfl_xor(m, off, 64));
    int lane = threadIdx.x & 63, wid = threadIdx.x >> 6;
    if (lane == 0) red[wid] = m;
    __syncthreads();
    m = fmaxf(fmaxf(red[0], red[1]), fmaxf(red[2], red[3]));
    float inv = m > 0.0f ? 127.0f / m : 0.0f;

    i8x16 q;
    #pragma unroll
    for (int j = 0; j < 16; ++j) {
        float qq = rintf(mv[j] * inv);
        qq = fminf(127.0f, fmaxf(-127.0f, qq));
        q[j] = (char)(int)qq;
    }
    *(i8x16*)(Wq + (size_t)o * K_DIM + threadIdx.x * 16) = q;
    if (threadIdx.x == 0) sw[o] = m > 0.0f ? m / 127.0f : 1.0f;
}

// ---------------------------------------------------------------------------
// Kernel 3: x f32 -> int8 with per-row symmetric scale. One block per row.
// ---------------------------------------------------------------------------
__global__ __launch_bounds__(256) void xq_kernel(const float* __restrict__ X,
                                                 int8_t* __restrict__ Xq,
                                                 float* __restrict__ sx) {
    __shared__ float red[4];
    int row = blockIdx.x;
    const float4* p = (const float4*)(X + (size_t)row * K_DIM) + threadIdx.x * 4;
    float4 v0 = p[0], v1 = p[1], v2 = p[2], v3 = p[3];
    float vv[16] = {v0.x, v0.y, v0.z, v0.w, v1.x, v1.y, v1.z, v1.w,
                    v2.x, v2.y, v2.z, v2.w, v3.x, v3.y, v3.z, v3.w};
    float m = 0.0f;
    #pragma unroll
    for (int j = 0; j < 16; ++j) m = fmaxf(m, fabsf(vv[j]));
    #pragma unroll
    for (int off = 32; off >= 1; off >>= 1) m = fmaxf(m, __shfl_xor(m, off, 64));
    int lane = threadIdx.x & 63, wid = threadIdx.x >> 6;
    if (lane == 0) red[wid] = m;
    __syncthreads();
    m = fmaxf(fmaxf(red[0], red[1]), fmaxf(red[2], red[3]));
    float inv = m > 0.0f ? 127.0f / m : 0.0f;

    i8x16 q;
    #pragma unroll
    for (int j = 0; j < 16; ++j) {
        float qq = rintf(vv[j] * inv);
        qq = fminf(127.0f, fmaxf(-127.0f, qq));
        q[j] = (char)(int)qq;
    }
    *(i8x16*)(Xq + (size_t)row * K_DIM + threadIdx.x * 16) = q;
    if (threadIdx.x == 0) sx[row] = m > 0.0f ? m / 127.0f : 1.0f;
}

// ---------------------------------------------------------------------------
// Kernel 4: 128x256 int8 GEMM, 2-blocks/CU WITHOUT spill (round-14 fix).
// 512 thr, 8 waves, wave tile 64x64 -> acc i32x4[4][4] = 64 regs; frags 32;
// total ~115 <= the 128-reg cap from __launch_bounds__(512,4). LDS 48KB
// (A 2x8KB + B 2x16KB dbuf) -> 2 blocks/CU = 96KB <= 160KB, 16 waves.
// Cross-block overlap (no shared barriers) is the mechanism: per slice-pair
// MFMA 2x653cy, LDS 2x768cy -> wall max~1536cy vs round-13 serial 2531cy.
// SP s: { 8 ds_read (region s&1) | stage s+1 (3 gload_lds) | lgkm(0) |
//         16 MFMA | CKPT0 | BAR }   (proven dbuf ledger: R@s covered by
// CKPT0@s-1+BAR; stage@s overwrites region of s-1 whose reads drained at
// lgkm(0)@s-1 before BAR@s-1. Tail SP63: no stage, no CKPT.)
// Frags 16x16x64 i8; XOR 16B-chunk swizzle (0 conflicts); XCD swizzle
// (1024 blocks % 8 == 0). Epilogue: C = sx[row]*sw[col]*acc + bias.
// ---------------------------------------------------------------------------
__global__ __launch_bounds__(512, 4) void gemm_i8(const int8_t* __restrict__ A,
                                                  const int8_t* __restrict__ B,
                                                  const float* __restrict__ sx,
                                                  const float* __restrict__ sw,
                                                  const float* __restrict__ bias,
                                                  float* __restrict__ C) {
    __shared__ __align__(16) unsigned char smem[49152]; // A:[0,16K) B:[16K,48K)

    int t    = threadIdx.x;
    int wid  = t >> 6;
    int lane = t & 63;
    int l16  = lane & 15;
    int lk   = lane >> 4;
    int wm   = wid >> 2;     // wave row-half of 128 (64 rows)
    int wn   = wid & 3;      // wave col-quarter of 256 (64 cols)

    // XCD-aware bijective swizzle (1024 blocks % 8 == 0)
    int bid = blockIdx.x;
    int swz = (bid & 7) * ((int)gridDim.x >> 3) + (bid >> 3);
    int bm  = swz >> 4;      // 0..63
    int bn  = swz & 15;      // 0..15

    // staging: thread t covers row r=t>>2; stored 16B chunk t&3 holds logical
    // chunk (t&3)^((r>>1)&3) = (t&3)^((t>>3)&3)
    int gch = ((t & 3) ^ ((t >> 3) & 3)) * 16;
    const int8_t* agbase = A + (size_t)(bm * 128 + (t >> 2)) * K_DIM + gch;
    const int8_t* bgbase = B + (size_t)(bn * 256 + (t >> 2)) * K_DIM + gch;

    auto stageAB = [&](int slice) {
        const int8_t* ga = agbase + slice * 64;
        const int8_t* gb = bgbase + slice * 64;
        char* la = (char*)smem + (slice & 1) * 8192 + wid * 1024;
        char* lb = (char*)smem + 16384 + (slice & 1) * 16384 + wid * 1024;
        __builtin_amdgcn_global_load_lds(AS_GLOBAL(ga), AS_LDS(la), 16, 0, 0);
        __builtin_amdgcn_global_load_lds(AS_GLOBAL(gb), AS_LDS(lb), 16, 0, 0);
        __builtin_amdgcn_global_load_lds(AS_GLOBAL(gb + (size_t)128 * K_DIM), AS_LDS(lb + 8192), 16, 0, 0);
    };

    // read-side: row R = base+l16, 16B chunk lk -> phys chunk lk^((l16>>1)&3)
    int koff = ((lk ^ ((l16 >> 1) & 3)) << 4);
    const char* ardb = (const char*)smem + (wm * 64 + l16) * 64 + koff;
    const char* brdb = (const char*)smem + 16384 + (wn * 64 + l16) * 64 + koff;

    i32x4 acc[4][4] = {};
    i32x4 af[4], bfr[4];

#define LGKM0() { asm volatile("s_waitcnt lgkmcnt(0)" ::: "memory");                 \
                  __builtin_amdgcn_sched_barrier(0); }
#define CKPT0() { asm volatile("s_waitcnt vmcnt(0)" ::: "memory");                   \
                  __builtin_amdgcn_sched_barrier(0); }
#define BAR()   { __builtin_amdgcn_s_barrier(); __builtin_amdgcn_sched_barrier(0); }

    // SP body. RN: region (s&1). SS: slice staged (s+1). DOSTAGE. CK.
#define SP(RN, SS, DOSTAGE, CK)                                                      \
    {                                                                                \
        const char* abase = ardb + (RN) * 8192;                                      \
        const char* bbase = brdb + (RN) * 16384;                                     \
        _Pragma("unroll")                                                            \
        for (int g = 0; g < 4; ++g) bfr[g] = *(const i32x4*)(bbase + g * 1024);      \
        _Pragma("unroll")                                                            \
        for (int i = 0; i < 4; ++i) af[i] = *(const i32x4*)(abase + i * 1024);       \
        if (DOSTAGE) stageAB(SS);                                                    \
        LGKM0()                                                                      \
        __builtin_amdgcn_s_setprio(1);                                               \
        _Pragma("unroll")                                                            \
        for (int i = 0; i < 4; ++i)                                                  \
            _Pragma("unroll")                                                        \
            for (int g = 0; g < 4; ++g)                                              \
                acc[i][g] = __builtin_amdgcn_mfma_i32_16x16x64_i8(af[i], bfr[g], acc[i][g], 0, 0, 0); \
        __builtin_amdgcn_s_setprio(0);                                               \
        __builtin_amdgcn_sched_barrier(0);                                           \
        if (CK) { CKPT0() }                                                          \
        BAR()                                                                        \
    }

    // prologue: slice 0 -> region 0; drain; sync
    stageAB(0);
    CKPT0()
    BAR()

    // 64 slices of 64 K-bytes; stage s+1 at SP s for s <= 62
    for (int s2 = 0; s2 < 31; ++s2) {
        int s = s2 * 2;
        SP(0, s + 1, 1, 1)
        SP(1, s + 2, 1, 1)
    }
    SP(0, 63, 1, 1)   // s=62: stage 63
    SP(1, 0,  0, 0)   // s=63: no stage, nothing outstanding

    // epilogue: C/D layout col = lane&15, row = (lane>>4)*4 + reg.
    // out = sx[row]*sw[col]*acc + bias.
    int    colb = bn * 256 + wn * 64;
    size_t rowb = (size_t)bm * 128 + wm * 64 + (lk << 2);
    #pragma unroll
    for (int g = 0; g < 4; ++g) {
        int col = colb + g * 16 + l16;
        float scw = sw[col];
        float bv  = bias[col];
        #pragma unroll
        for (int f = 0; f < 4; ++f) {
            size_t r0 = rowb + f * 16;
            #pragma unroll
            for (int rg = 0; rg < 4; ++rg)
                C[(r0 + rg) * N_DIM + col] = (float)acc[f][g][rg] * (sx[r0 + rg] * scw) + bv;
        }
    }
}

extern "C" void kernel_launch(void* const* d_in, const int* in_sizes, int n_in,
                              void* d_out, int out_size, void* d_ws, size_t ws_size,
                              hipStream_t stream) {
    const float* x    = (const float*)d_in[0];
    const float* W    = (const float*)d_in[1];
    const float* bias = (const float*)d_in[2];
    float* out = (float*)d_out;

    char* ws = (char*)d_ws;
    int8_t*   xq  = (int8_t*)ws;                                             // 32 MB
    int8_t*   wq  = (int8_t*)(ws + (size_t)M_DIM * K_DIM);                   // 16 MB
    uint16_t* sel = (uint16_t*)(ws + (size_t)M_DIM * K_DIM
                                   + (size_t)N_DIM * K_DIM);                 // 64 KB
    float*    sx  = (float*)((char*)sel + (size_t)(M_DIM / 64) * CBN * 2);   // 32 KB
    float*    sw  = (float*)((char*)sx + (size_t)M_DIM * 4);                 // 16 KB

    venom_sel  <<<dim3(64, 16), 256, 0, stream>>>(W, sel);
    venom_packq<<<dim3(N_DIM), 256, 0, stream>>>(W, sel, wq, sw);
    xq_kernel  <<<dim3(M_DIM), 256, 0, stream>>>(x, xq, sx);
    gemm_i8    <<<dim3((M_DIM / 128) * (N_DIM / 256)), 512, 0, stream>>>(xq, wq, sx, sw, bias, out);
}

// Round 16
// 195.628 us; speedup vs baseline: 7.8471x; 1.0797x over previous
//
#include <hip/hip_runtime.h>
#include <stdint.h>

#define M_DIM 8192
#define N_DIM 4096
#define K_DIM 4096
#define CBN   (K_DIM/8)   // 512 column groups per row

typedef __attribute__((ext_vector_type(4)))  int   i32x4;
typedef __attribute__((ext_vector_type(16))) char  i8x16;

#define AS_GLOBAL(p) (const __attribute__((address_space(1))) void*)(p)
#define AS_LDS(p)    (__attribute__((address_space(3))) void*)(p)

// ---------------------------------------------------------------------------
// Kernel 1: per (ob, cb) pick top-4 columns (of 8) by L1 mass over 64 rows.
// ---------------------------------------------------------------------------
__global__ __launch_bounds__(256) void venom_sel(const float* __restrict__ W,
                                                 uint16_t* __restrict__ sel) {
    int t   = threadIdx.x;
    int ob  = blockIdx.x;
    int col = blockIdx.y * 256 + t;
    const float* p = W + (size_t)(ob * 64) * K_DIM + col;
    double s = 0.0;
    #pragma unroll 16
    for (int r = 0; r < 64; ++r) s += fabsf(p[(size_t)r * K_DIM]);

    int lane = t & 63;
    int base = lane & ~7;
    double sc[8];
    #pragma unroll
    for (int j = 0; j < 8; ++j) sc[j] = __shfl(s, base + j, 64);

    uint32_t packed = 0;
    #pragma unroll
    for (int c = 0; c < 8; ++c) {
        int rank = 0;
        #pragma unroll
        for (int j = 0; j < 8; ++j)
            rank += (sc[j] > sc[c]) || (sc[j] == sc[c] && j < c);
        if (rank < 4) packed |= (uint32_t)c << (4 * rank);
    }
    if ((lane & 7) == 0) {
        int cb = col >> 3;
        sel[ob * CBN + cb] = (uint16_t)packed;
    }
}

// ---------------------------------------------------------------------------
// Kernel 2: masked weight -> int8 with per-output-row symmetric scale.
// ---------------------------------------------------------------------------
__global__ __launch_bounds__(256) void venom_packq(const float* __restrict__ W,
                                                   const uint16_t* __restrict__ sel,
                                                   int8_t* __restrict__ Wq,
                                                   float* __restrict__ sw) {
    __shared__ float red[4];
    int o = blockIdx.x;
    const float* rowp = W + (size_t)o * K_DIM;
    float mv[16];
    float m = 0.0f;
    #pragma unroll
    for (int h = 0; h < 2; ++h) {
        int cb = threadIdx.x * 2 + h;
        uint32_t pk = sel[(o >> 6) * CBN + cb];
        const float* p = rowp + cb * 8;
        float4 a = *(const float4*)p;
        float4 b = *(const float4*)(p + 4);
        float w[8] = {a.x, a.y, a.z, a.w, b.x, b.y, b.z, b.w};
        int   c[4]; float v[4];
        #pragma unroll
        for (int pz = 0; pz < 4; ++pz) {
            c[pz] = (pk >> (4 * pz)) & 7;
            v[pz] = fabsf(w[c[pz]]);
        }
        uint32_t keep = 0;
        #pragma unroll
        for (int pz = 0; pz < 4; ++pz) {
            int cnt = 0;
            #pragma unroll
            for (int q = 0; q < 4; ++q)
                cnt += (v[q] > v[pz]) || (v[q] == v[pz] && q < pz);
            if (cnt < 2) keep |= 1u << c[pz];
        }
        #pragma unroll
        for (int j = 0; j < 8; ++j) {
            float x = ((keep >> j) & 1) ? w[j] : 0.0f;
            mv[h * 8 + j] = x;
            m = fmaxf(m, fabsf(x));
        }
    }
    #pragma unroll
    for (int off = 32; off >= 1; off >>= 1) m = fmaxf(m, __shfl_xor(m, off, 64));
    int lane = threadIdx.x & 63, wid = threadIdx.x >> 6;
    if (lane == 0) red[wid] = m;
    __syncthreads();
    m = fmaxf(fmaxf(red[0], red[1]), fmaxf(red[2], red[3]));
    float inv = m > 0.0f ? 127.0f / m : 0.0f;

    i8x16 q;
    #pragma unroll
    for (int j = 0; j < 16; ++j) {
        float qq = rintf(mv[j] * inv);
        qq = fminf(127.0f, fmaxf(-127.0f, qq));
        q[j] = (char)(int)qq;
    }
    *(i8x16*)(Wq + (size_t)o * K_DIM + threadIdx.x * 16) = q;
    if (threadIdx.x == 0) sw[o] = m > 0.0f ? m / 127.0f : 1.0f;
}

// ---------------------------------------------------------------------------
// Kernel 3: x f32 -> int8 with per-row symmetric scale. One block per row.
// ---------------------------------------------------------------------------
__global__ __launch_bounds__(256) void xq_kernel(const float* __restrict__ X,
                                                 int8_t* __restrict__ Xq,
                                                 float* __restrict__ sx) {
    __shared__ float red[4];
    int row = blockIdx.x;
    const float4* p = (const float4*)(X + (size_t)row * K_DIM) + threadIdx.x * 4;
    float4 v0 = p[0], v1 = p[1], v2 = p[2], v3 = p[3];
    float vv[16] = {v0.x, v0.y, v0.z, v0.w, v1.x, v1.y, v1.z, v1.w,
                    v2.x, v2.y, v2.z, v2.w, v3.x, v3.y, v3.z, v3.w};
    float m = 0.0f;
    #pragma unroll
    for (int j = 0; j < 16; ++j) m = fmaxf(m, fabsf(vv[j]));
    #pragma unroll
    for (int off = 32; off >= 1; off >>= 1) m = fmaxf(m, __shfl_xor(m, off, 64));
    int lane = threadIdx.x & 63, wid = threadIdx.x >> 6;
    if (lane == 0) red[wid] = m;
    __syncthreads();
    m = fmaxf(fmaxf(red[0], red[1]), fmaxf(red[2], red[3]));
    float inv = m > 0.0f ? 127.0f / m : 0.0f;

    i8x16 q;
    #pragma unroll
    for (int j = 0; j < 16; ++j) {
        float qq = rintf(vv[j] * inv);
        qq = fminf(127.0f, fmaxf(-127.0f, qq));
        q[j] = (char)(int)qq;
    }
    *(i8x16*)(Xq + (size_t)row * K_DIM + threadIdx.x * 16) = q;
    if (threadIdx.x == 0) sx[row] = m > 0.0f ? m / 127.0f : 1.0f;
}

// ---------------------------------------------------------------------------
// Kernel 4: 256x256 int8 GEMM — round-13 structure, COMPILER-SCHEDULED inner
// body. Change vs round 13 (single variable): the intra-SP pins are removed —
// no lgkm(0) asm, no sched_barrier/setprio around the MFMA cluster. The
// compiler then emits counted lgkmcnt(N) between each ds_read and its
// dependent MFMA (m97-verified behavior), interleaving MFMA execution with
// the LDS service of later reads — the within-wave read∥MFMA overlap that
// the pinned variants (rounds 3-15, all ~50% MfmaUtil, wall = LDS+MFMA sum)
// structurally forbade (m141's lesson: sched_barrier(0) pinning defeats the
// scheduler).
// Correctness skeleton kept: stage = side-effecting builtins (compiler won't
// reorder LDS ops across them, conservative aliasing); CKPT4/CKPT0 = asm with
// memory clobber (full compiler memory fence: ds_reads cannot cross); BAR +
// one sched_barrier at SP boundary. The vmcnt ledger is round 13's, verified:
//   R@SP s (region s&3): staged @s-2, drained CKPT4@s-1 (outstanding 8 ->
//   oldest 4 = slice s) + BAR. W-after-R: stage s+2 overwrites region of
//   slice s-2, read @SP s-2, drained >=2 barriers earlier.
//   Tail: SP62 CKPT0 (drains stage@61 = slice 63), SP63 no stage/CKPT.
// Frags 16x16x64 i8; XOR 16B-chunk swizzle (0 conflicts); XCD block swizzle.
// Epilogue: C = sx[row]*sw[col]*acc + bias.
// ---------------------------------------------------------------------------
__global__ __launch_bounds__(512, 2) void gemm256_i8(const int8_t* __restrict__ A,
                                                     const int8_t* __restrict__ B,
                                                     const float* __restrict__ sx,
                                                     const float* __restrict__ sw,
                                                     const float* __restrict__ bias,
                                                     float* __restrict__ C) {
    __shared__ __align__(16) unsigned char smem[131072]; // A:[0,64K) B:[64K,128K)

    int t    = threadIdx.x;
    int wid  = t >> 6;
    int lane = t & 63;
    int l16  = lane & 15;
    int lk   = lane >> 4;
    int wm   = wid >> 2;     // wave row-half (128 rows)
    int wn   = wid & 3;      // wave col-quarter (64 cols)

    // XCD-aware bijective swizzle (512 blocks % 8 == 0)
    int bid = blockIdx.x;
    int swz = (bid & 7) * ((int)gridDim.x >> 3) + (bid >> 3);
    int bm  = swz >> 4;
    int bn  = swz & 15;

    // staging: thread t covers row r=t>>2 (and r+128); stored 16B chunk t&3
    // holds logical chunk (t&3)^((r>>1)&3) = (t&3)^((t>>3)&3)
    int gch = ((t & 3) ^ ((t >> 3) & 3)) * 16;
    const int8_t* agbase = A + (size_t)(bm * 256 + (t >> 2)) * K_DIM + gch;
    const int8_t* bgbase = B + (size_t)(bn * 256 + (t >> 2)) * K_DIM + gch;

    auto stageA2 = [&](int slice) {
        const int8_t* ga = agbase + slice * 64;
        char* la = (char*)smem + (slice & 3) * 16384 + wid * 1024;
        __builtin_amdgcn_global_load_lds(AS_GLOBAL(ga), AS_LDS(la), 16, 0, 0);
        __builtin_amdgcn_global_load_lds(AS_GLOBAL(ga + (size_t)128 * K_DIM), AS_LDS(la + 8192), 16, 0, 0);
    };
    auto stageB2 = [&](int slice) {
        const int8_t* gb = bgbase + slice * 64;
        char* lb = (char*)smem + 65536 + (slice & 3) * 16384 + wid * 1024;
        __builtin_amdgcn_global_load_lds(AS_GLOBAL(gb), AS_LDS(lb), 16, 0, 0);
        __builtin_amdgcn_global_load_lds(AS_GLOBAL(gb + (size_t)128 * K_DIM), AS_LDS(lb + 8192), 16, 0, 0);
    };

    // read-side: row R = base+l16, 16B chunk lk -> phys chunk lk^((l16>>1)&3)
    int koff = ((lk ^ ((l16 >> 1) & 3)) << 4);
    const char* ardb = (const char*)smem + (wm * 128 + l16) * 64 + koff;
    const char* brdb = (const char*)smem + 65536 + (wn * 64 + l16) * 64 + koff;

    i32x4 acc[8][4] = {};
    i32x4 af0[4], af1[4], bfr[4];

#define CKPT4() { asm volatile("s_waitcnt vmcnt(4)" ::: "memory"); }
#define CKPT0() { asm volatile("s_waitcnt vmcnt(0)" ::: "memory"); }
#define BAR()   { __builtin_amdgcn_s_barrier(); __builtin_amdgcn_sched_barrier(0); }

    // SP body — UNPINNED: compiler schedules ds_reads, stages, and MFMAs
    // freely within the region; register dependencies generate the counted
    // lgkmcnt waits. RN: region (s&3). SS: slice staged (s+2). DOSTAGE. CK.
#define SP(RN, SS, DOSTAGE, CK)                                                      \
    {                                                                                \
        const char* abase = ardb + (RN) * 16384;                                     \
        const char* bbase = brdb + (RN) * 16384;                                     \
        _Pragma("unroll")                                                            \
        for (int g = 0; g < 4; ++g) bfr[g] = *(const i32x4*)(bbase + g * 1024);      \
        _Pragma("unroll")                                                            \
        for (int i = 0; i < 4; ++i) af0[i] = *(const i32x4*)(abase + i * 1024);      \
        _Pragma("unroll")                                                            \
        for (int i = 0; i < 4; ++i) af1[i] = *(const i32x4*)(abase + 4096 + i * 1024); \
        if (DOSTAGE) { stageA2(SS); stageB2(SS); }                                   \
        _Pragma("unroll")                                                            \
        for (int i = 0; i < 4; ++i)                                                  \
            _Pragma("unroll")                                                        \
            for (int g = 0; g < 4; ++g)                                              \
                acc[i][g] = __builtin_amdgcn_mfma_i32_16x16x64_i8(af0[i], bfr[g], acc[i][g], 0, 0, 0); \
        _Pragma("unroll")                                                            \
        for (int i = 0; i < 4; ++i)                                                  \
            _Pragma("unroll")                                                        \
            for (int g = 0; g < 4; ++g)                                              \
                acc[4+i][g] = __builtin_amdgcn_mfma_i32_16x16x64_i8(af1[i], bfr[g], acc[4+i][g], 0, 0, 0); \
        if ((CK) == 4) { CKPT4() } else if ((CK) == 1) { CKPT0() }                   \
        BAR()                                                                        \
    }

    // prologue: slices 0,1 -> regions 0,1; drain slice 0 (8 outstanding); sync
    stageA2(0); stageB2(0);
    stageA2(1); stageB2(1);
    CKPT4()
    BAR()

    // 64 slices of 64 K-bytes; stages at SP <= 61 (slice s+2 <= 63)
    for (int s4 = 0; s4 < 15; ++s4) {
        int s = s4 * 4;
        SP(0, s + 2, 1, 4)
        SP(1, s + 3, 1, 4)
        SP(2, s + 4, 1, 4)
        SP(3, s + 5, 1, 4)
    }
    SP(0, 62, 1, 4)   // s=60
    SP(1, 63, 1, 4)   // s=61
    SP(2, 0,  0, 1)   // s=62: CKPT0 drains stage@61 (slice 63) for SP63
    SP(3, 0,  0, 0)   // s=63

    // epilogue: C/D layout col = lane&15, row = (lane>>4)*4 + reg.
    // out = sx[row]*sw[col]*acc + bias.
    int    colb = bn * 256 + wn * 64;
    size_t rowb = (size_t)bm * 256 + wm * 128 + (lk << 2);
    float sxv[8][4];
    #pragma unroll
    for (int f = 0; f < 8; ++f)
        #pragma unroll
        for (int rg = 0; rg < 4; ++rg)
            sxv[f][rg] = sx[rowb + f * 16 + rg];
    #pragma unroll
    for (int g = 0; g < 4; ++g) {
        int col = colb + g * 16 + l16;
        float scw = sw[col];
        float bv  = bias[col];
        #pragma unroll
        for (int f = 0; f < 8; ++f) {
            size_t r0 = rowb + f * 16;
            #pragma unroll
            for (int rg = 0; rg < 4; ++rg)
                C[(r0 + rg) * N_DIM + col] = (float)acc[f][g][rg] * (sxv[f][rg] * scw) + bv;
        }
    }
}

extern "C" void kernel_launch(void* const* d_in, const int* in_sizes, int n_in,
                              void* d_out, int out_size, void* d_ws, size_t ws_size,
                              hipStream_t stream) {
    const float* x    = (const float*)d_in[0];
    const float* W    = (const float*)d_in[1];
    const float* bias = (const float*)d_in[2];
    float* out = (float*)d_out;

    char* ws = (char*)d_ws;
    int8_t*   xq  = (int8_t*)ws;                                             // 32 MB
    int8_t*   wq  = (int8_t*)(ws + (size_t)M_DIM * K_DIM);                   // 16 MB
    uint16_t* sel = (uint16_t*)(ws + (size_t)M_DIM * K_DIM
                                   + (size_t)N_DIM * K_DIM);                 // 64 KB
    float*    sx  = (float*)((char*)sel + (size_t)(M_DIM / 64) * CBN * 2);   // 32 KB
    float*    sw  = (float*)((char*)sx + (size_t)M_DIM * 4);                 // 16 KB

    venom_sel  <<<dim3(64, 16), 256, 0, stream>>>(W, sel);
    venom_packq<<<dim3(N_DIM), 256, 0, stream>>>(W, sel, wq, sw);
    xq_kernel  <<<dim3(M_DIM), 256, 0, stream>>>(x, xq, sx);
    gemm256_i8 <<<dim3((M_DIM / 256) * (N_DIM / 256)), 512, 0, stream>>>(xq, wq, sx, sw, bias, out);
}